// Round 9
// baseline (72.153 us; speedup 1.0000x reference)
//
#include <hip/hip_runtime.h>
#include <stdint.h>

#define DD 512
#define NP 1024
#define NB 16

typedef __attribute__((ext_vector_type(8))) __bf16 bf16x8;
typedef __attribute__((ext_vector_type(4))) float f32x4;

// ws layout (floats): qhw [16384][64] (4MB) | khw [16][64][1024] (4MB)
//                     | tbl bf16 [2][64][256] pre-swizzled (64KB) | G f32 [64][64]

__device__ __forceinline__ bf16x8 cvt8(const float4& a, const float4& b) {
    bf16x8 r;
    r[0]=(__bf16)a.x; r[1]=(__bf16)a.y; r[2]=(__bf16)a.z; r[3]=(__bf16)a.w;
    r[4]=(__bf16)b.x; r[5]=(__bf16)b.y; r[6]=(__bf16)b.z; r[7]=(__bf16)b.w;
    return r;
}

__device__ __forceinline__ void gload_lds16(const void* g, void* l) {
    __builtin_amdgcn_global_load_lds(
        (const __attribute__((address_space(1))) unsigned int*)g,
        (__attribute__((address_space(3))) unsigned int*)l,
        16, 0, 0);
}

// EHW row r: r<32 -> embed[r*32][col..]; r>=32 -> embed[r-32][col..] - embed[0][col..]
__device__ __forceinline__ bf16x8 ehw_row(const float* __restrict__ embed, int r,
                                          int col, const float4& z0, const float4& z1) {
    int srcrow = (r < 32) ? (r << 5) : (r - 32);
    const float* sp = embed + (size_t)srcrow * DD + col;
    float4 a = *(const float4*)sp;
    float4 b = *(const float4*)(sp + 4);
    if (r >= 32) {
        a.x -= z0.x; a.y -= z0.y; a.z -= z0.z; a.w -= z0.w;
        b.x -= z1.x; b.y -= z1.y; b.z -= z1.z; b.w -= z1.w;
    }
    return cvt8(a, b);
}

// ---------- prep: blocks 0..15 build pre-swizzled bf16 table; block 16 builds G ----
__global__ __launch_bounds__(256) void prep(
    const float* __restrict__ embed, unsigned short* __restrict__ tbl,
    float* __restrict__ G)
{
    const int tid = threadIdx.x;
    if (blockIdx.x < 16) {
        int g = blockIdx.x * 256 + tid;        // 0..4095
        int row = g >> 6;                      // 0..63
        int c8  = (g & 63) * 8;                // 0..504
        float4 z0 = *(const float4*)(embed + c8);
        float4 z1 = *(const float4*)(embed + c8 + 4);
        bf16x8 r = ehw_row(embed, row, c8, z0, z1);
        int h  = c8 >> 8;
        int cl = c8 & 255;
        int byte = (cl * 2) ^ ((row & 7) << 4);          // bake LDS swizzle
        *(bf16x8*)((char*)tbl + h * 32768 + row * 512 + byte) = r;
    } else {
        // G = EHW . EHW^T (64x64)
        const int lane = tid & 63, wid = tid >> 6;
        const int lr = lane & 15, kq = (lane >> 4) * 8;
        f32x4 acc[4];
        #pragma unroll
        for (int n = 0; n < 4; ++n) acc[n] = (f32x4)0.0f;
        for (int ks = 0; ks < 16; ++ks) {
            int col = ks * 32 + kq;
            float4 z0 = *(const float4*)(embed + col);
            float4 z1 = *(const float4*)(embed + col + 4);
            bf16x8 af = ehw_row(embed, wid * 16 + lr, col, z0, z1);
            #pragma unroll
            for (int n = 0; n < 4; ++n) {
                bf16x8 bf = ehw_row(embed, n * 16 + lr, col, z0, z1);
                acc[n] = __builtin_amdgcn_mfma_f32_16x16x32_bf16(af, bf, acc[n], 0, 0, 0);
            }
        }
        int row0 = wid * 16 + (lane >> 4) * 4;
        #pragma unroll
        for (int n = 0; n < 4; ++n)
            #pragma unroll
            for (int i = 0; i < 4; ++i)
                G[(size_t)(row0 + i) * 64 + n * 16 + lr] = acc[n][i];
    }
}

// ---------- rank_gemm: 32 streamed rows/block, 32KB LDS, zero block barriers ----
// blocks 0..511:    qhw[P][m]    = q[P,:]·EHW[m,:]      (32 P-rows per block)
// blocks 512..1023: khw[b][m][Q] = EHW[m,:]·k[b,Q,:]    (32 Q-rows per block)
// wave w owns table rows [16w,16w+16): stages ONLY those, reads ONLY those.
__global__ __launch_bounds__(256) void rank_gemm(
    const float* __restrict__ q, const float* __restrict__ kin,
    const unsigned short* __restrict__ tbl,
    float* __restrict__ qhw, float* __restrict__ khw)
{
    __shared__ __align__(16) unsigned short T[64 * 256];   // 32 KB (one K-half)

    const int tid = threadIdx.x, lane = tid & 63, wid = tid >> 6;
    const int lr = lane & 15, kq = (lane >> 4) * 8;
    const int gsel = blockIdx.x >> 9;
    const int tile = blockIdx.x & 511;
    const int tw = wid * 16;                   // this wave's table-row base

    const int grow = tile * 32;                // first streamed row (0..16352)
    const float* s0 = (gsel ? kin : q) + (size_t)(grow + lr) * DD + kq;

    f32x4 acc0 = (f32x4)0.0f, acc1 = (f32x4)0.0f;

    #pragma unroll
    for (int half = 0; half < 2; ++half) {
        if (half) {
            // wave-local: all ds_reads of half 0 retired before overwriting
            asm volatile("s_waitcnt lgkmcnt(0)" ::: "memory");
            __builtin_amdgcn_sched_barrier(0);
        }
        // stage this wave's 16 rows of this K-half (8 KB, linear DMA)
        #pragma unroll
        for (int c = 0; c < 8; ++c) {
            int off = tw * 512 + c * 1024;
            gload_lds16((const char*)tbl + half * 32768 + off + lane * 16,
                        (char*)T + off);
        }
        asm volatile("s_waitcnt vmcnt(0)" ::: "memory");
        __builtin_amdgcn_sched_barrier(0);

        #pragma unroll
        for (int ks = 0; ks < 8; ++ks) {
            const float* sa = s0 + half * 256 + ks * 32;
            float4 a0 = *(const float4*)sa;
            float4 a1 = *(const float4*)(sa + 4);
            float4 b0 = *(const float4*)(sa + 16 * DD);
            float4 b1 = *(const float4*)(sa + 16 * DD + 4);
            bf16x8 sf0 = cvt8(a0, a1);
            bf16x8 sf1 = cvt8(b0, b1);
            const int row = tw + lr;
            const int kb = (ks * 32 + kq) * 2;
            bf16x8 ef = *(const bf16x8*)((const char*)T + row * 512 +
                                         (kb ^ ((row & 7) << 4)));
            if (!gsel) {
                acc0 = __builtin_amdgcn_mfma_f32_16x16x32_bf16(sf0, ef, acc0, 0, 0, 0);
                acc1 = __builtin_amdgcn_mfma_f32_16x16x32_bf16(sf1, ef, acc1, 0, 0, 0);
            } else {
                acc0 = __builtin_amdgcn_mfma_f32_16x16x32_bf16(ef, sf0, acc0, 0, 0, 0);
                acc1 = __builtin_amdgcn_mfma_f32_16x16x32_bf16(ef, sf1, acc1, 0, 0, 0);
            }
        }
    }

    if (!gsel) {
        // C row -> streamed P (rg*16 + (lane>>4)*4 + i), C col -> table m = tw+lr
        float* o = qhw + (size_t)(grow + (lane >> 4) * 4) * 64 + tw + lr;
        #pragma unroll
        for (int i = 0; i < 4; ++i) o[(size_t)i * 64]          = acc0[i];
        #pragma unroll
        for (int i = 0; i < 4; ++i) o[(size_t)(16 + i) * 64]   = acc1[i];
    } else {
        // C row -> table m = tw + (lane>>4)*4 + i, C col -> streamed Q
        int b = grow >> 10, Q0 = grow & 1023;
        float* o = khw + (size_t)b * 65536
                 + (size_t)(tw + (lane >> 4) * 4) * 1024 + Q0 + lr;
        #pragma unroll
        for (int i = 0; i < 4; ++i) o[(size_t)i * 1024]        = acc0[i];
        #pragma unroll
        for (int i = 0; i < 4; ++i) o[(size_t)i * 1024 + 16]   = acc1[i];
    }
}

// ---------- assemble: minimal writer ----------
// out[b][P=(i,j)][Q=(kq,lq)] = kh[i][Q] + kw[j][Q] + d1[jj][kq] + d2[jj][lq]
__global__ __launch_bounds__(256) void assemble(
    const float* __restrict__ qhw, const float* __restrict__ khw,
    const float* __restrict__ G, float* __restrict__ out)
{
    __shared__ __align__(16) float kh[NP];     // 4 KB
    __shared__ __align__(16) float d1[16][32];
    __shared__ __align__(16) float d2[16][32];

    const int tid = threadIdx.x, wid = tid >> 6, lane = tid & 63;
    const int b  = blockIdx.x >> 6;
    const int i  = (blockIdx.x >> 1) & 31;
    const int jh = blockIdx.x & 1;

    gload_lds16((const char*)(khw + (size_t)b * 65536 + (size_t)i * 1024)
                    + wid * 1024 + lane * 16,
                (char*)kh + wid * 1024);

    {
        int jj = tid >> 4, c = tid & 15;
        int j  = jh * 16 + jj;
        size_t Prow = (size_t)b * NP + i * 32 + j;
        const float* qA = qhw + Prow * 64;
        const float* Gi = G + (size_t)i * 64;
        const float* Gj = G + (size_t)(32 + j) * 64;
        d1[jj][c]      = qA[c]      + Gi[c]      + Gj[c];
        d1[jj][c + 16] = qA[c + 16] + Gi[c + 16] + Gj[c + 16];
        d2[jj][c]      = qA[32 + c] + Gi[32 + c] + Gj[32 + c];
        d2[jj][c + 16] = qA[48 + c] + Gi[48 + c] + Gj[48 + c];
    }
    __syncthreads();

    const int Q0 = tid * 4;
    const int kidx = Q0 >> 5;
    const int lidx = Q0 & 31;
    const float4 khv = *(const float4*)&kh[Q0];

    float* orow = out + ((size_t)b * NP + i * 32 + jh * 16) * NP + Q0;
    const float* kwb = khw + (size_t)b * 65536 + (size_t)(32 + jh * 16) * 1024 + Q0;

    #pragma unroll 4
    for (int jj = 0; jj < 16; ++jj) {
        float4 kw = *(const float4*)(kwb + (size_t)jj * 1024);
        float  s1 = d1[jj][kidx];
        float4 s2 = *(const float4*)&d2[jj][lidx];
        f32x4 v;
        v.x = khv.x + kw.x + s1 + s2.x;
        v.y = khv.y + kw.y + s1 + s2.y;
        v.z = khv.z + kw.z + s1 + s2.z;
        v.w = khv.w + kw.w + s1 + s2.w;
        __builtin_nontemporal_store(v, (f32x4*)(orow + (size_t)jj * NP));
    }
}

extern "C" void kernel_launch(void* const* d_in, const int* in_sizes, int n_in,
                              void* d_out, int out_size, void* d_ws, size_t ws_size,
                              hipStream_t stream) {
    const float* q = (const float*)d_in[0];
    const float* k = (const float*)d_in[1];
    const float* e = (const float*)d_in[2];
    float* out = (float*)d_out;

    float* qhw = (float*)d_ws;                                    // 4 MB
    float* khw = qhw + (size_t)NB * NP * 64;                      // 4 MB
    unsigned short* tbl = (unsigned short*)(khw + (size_t)NB * 64 * NP); // 64 KB
    float* G = (float*)((char*)tbl + 65536);                      // 16 KB

    hipLaunchKernelGGL(prep,      dim3(17),   dim3(256), 0, stream, e, tbl, G);
    hipLaunchKernelGGL(rank_gemm, dim3(1024), dim3(256), 0, stream, q, k, tbl, qhw, khw);
    hipLaunchKernelGGL(assemble,  dim3(1024), dim3(256), 0, stream, qhw, khw, G, out);
}

// Round 10
// 53.211 us; speedup vs baseline: 1.3560x; 1.3560x over previous
//
#include <hip/hip_runtime.h>
#include <stdint.h>

#define DD 512
#define NP 1024
#define NB 16

typedef __attribute__((ext_vector_type(8))) __bf16 bf16x8;
typedef __attribute__((ext_vector_type(4))) float f32x4;

// ws layout (floats): qhw [16384][64] (4MB) | khw [16][64][1024] (4MB)
//                     | tbl bf16 [2][64][256] pre-swizzled (64KB) | G f32 [64][64]

__device__ __forceinline__ bf16x8 cvt8(const float4& a, const float4& b) {
    bf16x8 r;
    r[0]=(__bf16)a.x; r[1]=(__bf16)a.y; r[2]=(__bf16)a.z; r[3]=(__bf16)a.w;
    r[4]=(__bf16)b.x; r[5]=(__bf16)b.y; r[6]=(__bf16)b.z; r[7]=(__bf16)b.w;
    return r;
}

__device__ __forceinline__ void gload_lds16(const void* g, void* l) {
    __builtin_amdgcn_global_load_lds(
        (const __attribute__((address_space(1))) unsigned int*)g,
        (__attribute__((address_space(3))) unsigned int*)l,
        16, 0, 0);
}

// EHW row r: r<32 -> embed[r*32][col..]; r>=32 -> embed[r-32][col..] - embed[0][col..]
__device__ __forceinline__ bf16x8 ehw_row(const float* __restrict__ embed, int r,
                                          int col, const float4& z0, const float4& z1) {
    int srcrow = (r < 32) ? (r << 5) : (r - 32);
    const float* sp = embed + (size_t)srcrow * DD + col;
    float4 a = *(const float4*)sp;
    float4 b = *(const float4*)(sp + 4);
    if (r >= 32) {
        a.x -= z0.x; a.y -= z0.y; a.z -= z0.z; a.w -= z0.w;
        b.x -= z1.x; b.y -= z1.y; b.z -= z1.z; b.w -= z1.w;
    }
    return cvt8(a, b);
}

// ---------- prep: blocks 0..15 build pre-swizzled bf16 table; block 16 builds G ----
__global__ __launch_bounds__(256) void prep(
    const float* __restrict__ embed, unsigned short* __restrict__ tbl,
    float* __restrict__ G)
{
    const int tid = threadIdx.x;
    if (blockIdx.x < 16) {
        int g = blockIdx.x * 256 + tid;        // 0..4095
        int row = g >> 6;                      // 0..63
        int c8  = (g & 63) * 8;                // 0..504
        float4 z0 = *(const float4*)(embed + c8);
        float4 z1 = *(const float4*)(embed + c8 + 4);
        bf16x8 r = ehw_row(embed, row, c8, z0, z1);
        int h  = c8 >> 8;
        int cl = c8 & 255;
        int byte = (cl * 2) ^ ((row & 7) << 4);          // bake LDS swizzle
        *(bf16x8*)((char*)tbl + h * 32768 + row * 512 + byte) = r;
    } else {
        // G = EHW . EHW^T (64x64)
        const int lane = tid & 63, wid = tid >> 6;
        const int lr = lane & 15, kq = (lane >> 4) * 8;
        f32x4 acc[4];
        #pragma unroll
        for (int n = 0; n < 4; ++n) acc[n] = (f32x4)0.0f;
        for (int ks = 0; ks < 16; ++ks) {
            int col = ks * 32 + kq;
            float4 z0 = *(const float4*)(embed + col);
            float4 z1 = *(const float4*)(embed + col + 4);
            bf16x8 af = ehw_row(embed, wid * 16 + lr, col, z0, z1);
            #pragma unroll
            for (int n = 0; n < 4; ++n) {
                bf16x8 bf = ehw_row(embed, n * 16 + lr, col, z0, z1);
                acc[n] = __builtin_amdgcn_mfma_f32_16x16x32_bf16(af, bf, acc[n], 0, 0, 0);
            }
        }
        int row0 = wid * 16 + (lane >> 4) * 4;
        #pragma unroll
        for (int n = 0; n < 4; ++n)
            #pragma unroll
            for (int i = 0; i < 4; ++i)
                G[(size_t)(row0 + i) * 64 + n * 16 + lr] = acc[n][i];
    }
}

// ---------- rank_gemm: R8 structure, but 32KB LDS (K-half restaged in time) ----
// blocks 0..255:  qhw[P][m]    = q[P,:]·EHW[m,:]       (64 P-rows per block)
// blocks 256..511: khw[b][m][Q] = EHW[m,:]·k[b,Q,:]    (64 Q-rows per block)
__global__ __launch_bounds__(256) void rank_gemm(
    const float* __restrict__ q, const float* __restrict__ kin,
    const unsigned short* __restrict__ tbl,
    float* __restrict__ qhw, float* __restrict__ khw)
{
    __shared__ __align__(16) unsigned short T[64 * 256];   // 32 KB: one K-half

    const int tid = threadIdx.x, lane = tid & 63, wid = tid >> 6;
    const int lr = lane & 15, kq = (lane >> 4) * 8;
    const int gsel = blockIdx.x >> 8;
    const int tile = blockIdx.x & 255;

    const int grow = tile * 64 + wid * 16 + lr;            // distinct rows per wave
    const float* srcA = (gsel ? kin : q) + (size_t)grow * DD + kq;

    f32x4 acc[4];
    #pragma unroll
    for (int n = 0; n < 4; ++n) acc[n] = (f32x4)0.0f;

    #pragma unroll
    for (int half = 0; half < 2; ++half) {
        if (half) __syncthreads();     // all ds_reads of half 0 retired
        // stage this K-half of the table: 32 KB linear DMA
        #pragma unroll
        for (int c = 0; c < 8; ++c) {
            int off = c * 4096 + tid * 16;
            gload_lds16((const char*)tbl + half * 32768 + off, (char*)T + off);
        }
        __syncthreads();               // drains vmcnt before reads

        #pragma unroll
        for (int ks = 0; ks < 8; ++ks) {
            const float* sa = srcA + half * 256 + ks * 32;
            float4 a0 = *(const float4*)sa;
            float4 a1 = *(const float4*)(sa + 4);
            bf16x8 sf = cvt8(a0, a1);
            const int kb = (ks * 32 + kq) * 2;
            bf16x8 ef[4];
            #pragma unroll
            for (int n = 0; n < 4; ++n) {
                int row = n * 16 + lr;
                ef[n] = *(const bf16x8*)((const char*)T + row * 512 +
                                         (kb ^ ((row & 7) << 4)));
            }
            if (!gsel) {
                #pragma unroll
                for (int n = 0; n < 4; ++n)
                    acc[n] = __builtin_amdgcn_mfma_f32_16x16x32_bf16(sf, ef[n], acc[n], 0, 0, 0);
            } else {
                #pragma unroll
                for (int n = 0; n < 4; ++n)
                    acc[n] = __builtin_amdgcn_mfma_f32_16x16x32_bf16(ef[n], sf, acc[n], 0, 0, 0);
            }
        }
    }

    if (!gsel) {
        // C row -> streamed P, C col -> table m
        float* o = qhw + (size_t)(tile * 64 + wid * 16 + (lane >> 4) * 4) * 64 + lr;
        #pragma unroll
        for (int n = 0; n < 4; ++n)
            #pragma unroll
            for (int i = 0; i < 4; ++i)
                o[(size_t)i * 64 + n * 16] = acc[n][i];
    } else {
        // C row -> table m, C col -> streamed Q
        int b = grow >> 10, Q = grow & 1023;
        float* o = khw + (size_t)b * 65536 + Q;
        int m0 = (lane >> 4) * 4;
        #pragma unroll
        for (int n = 0; n < 4; ++n)
            #pragma unroll
            for (int i = 0; i < 4; ++i)
                o[(size_t)(n * 16 + m0 + i) * 1024] = acc[n][i];
    }
}

// ---------- assemble: minimal writer ----------
// out[b][P=(i,j)][Q=(kq,lq)] = kh[i][Q] + kw[j][Q] + d1[jj][kq] + d2[jj][lq]
__global__ __launch_bounds__(256) void assemble(
    const float* __restrict__ qhw, const float* __restrict__ khw,
    const float* __restrict__ G, float* __restrict__ out)
{
    __shared__ __align__(16) float kh[NP];     // 4 KB
    __shared__ __align__(16) float d1[16][32];
    __shared__ __align__(16) float d2[16][32];

    const int tid = threadIdx.x, wid = tid >> 6, lane = tid & 63;
    const int b  = blockIdx.x >> 6;
    const int i  = (blockIdx.x >> 1) & 31;
    const int jh = blockIdx.x & 1;

    gload_lds16((const char*)(khw + (size_t)b * 65536 + (size_t)i * 1024)
                    + wid * 1024 + lane * 16,
                (char*)kh + wid * 1024);

    {
        int jj = tid >> 4, c = tid & 15;
        int j  = jh * 16 + jj;
        size_t Prow = (size_t)b * NP + i * 32 + j;
        const float* qA = qhw + Prow * 64;
        const float* Gi = G + (size_t)i * 64;
        const float* Gj = G + (size_t)(32 + j) * 64;
        d1[jj][c]      = qA[c]      + Gi[c]      + Gj[c];
        d1[jj][c + 16] = qA[c + 16] + Gi[c + 16] + Gj[c + 16];
        d2[jj][c]      = qA[32 + c] + Gi[32 + c] + Gj[32 + c];
        d2[jj][c + 16] = qA[48 + c] + Gi[48 + c] + Gj[48 + c];
    }
    __syncthreads();

    const int Q0 = tid * 4;
    const int kidx = Q0 >> 5;
    const int lidx = Q0 & 31;
    const float4 khv = *(const float4*)&kh[Q0];

    float* orow = out + ((size_t)b * NP + i * 32 + jh * 16) * NP + Q0;
    const float* kwb = khw + (size_t)b * 65536 + (size_t)(32 + jh * 16) * 1024 + Q0;

    #pragma unroll 4
    for (int jj = 0; jj < 16; ++jj) {
        float4 kw = *(const float4*)(kwb + (size_t)jj * 1024);
        float  s1 = d1[jj][kidx];
        float4 s2 = *(const float4*)&d2[jj][lidx];
        f32x4 v;
        v.x = khv.x + kw.x + s1 + s2.x;
        v.y = khv.y + kw.y + s1 + s2.y;
        v.z = khv.z + kw.z + s1 + s2.z;
        v.w = khv.w + kw.w + s1 + s2.w;
        __builtin_nontemporal_store(v, (f32x4*)(orow + (size_t)jj * NP));
    }
}

extern "C" void kernel_launch(void* const* d_in, const int* in_sizes, int n_in,
                              void* d_out, int out_size, void* d_ws, size_t ws_size,
                              hipStream_t stream) {
    const float* q = (const float*)d_in[0];
    const float* k = (const float*)d_in[1];
    const float* e = (const float*)d_in[2];
    float* out = (float*)d_out;

    float* qhw = (float*)d_ws;                                    // 4 MB
    float* khw = qhw + (size_t)NB * NP * 64;                      // 4 MB
    unsigned short* tbl = (unsigned short*)(khw + (size_t)NB * 64 * NP); // 64 KB
    float* G = (float*)((char*)tbl + 65536);                      // 16 KB

    hipLaunchKernelGGL(prep,      dim3(17),  dim3(256), 0, stream, e, tbl, G);
    hipLaunchKernelGGL(rank_gemm, dim3(512), dim3(256), 0, stream, q, k, tbl, qhw, khw);
    hipLaunchKernelGGL(assemble,  dim3(1024), dim3(256), 0, stream, qhw, khw, G, out);
}

// Round 11
// 52.983 us; speedup vs baseline: 1.3618x; 1.0043x over previous
//
#include <hip/hip_runtime.h>
#include <stdint.h>

#define DD 512
#define NP 1024
#define NB 16
#define PF 6   // stream prefetch depth (steps); 2 float4 loads per step

typedef __attribute__((ext_vector_type(8))) __bf16 bf16x8;
typedef __attribute__((ext_vector_type(4))) float f32x4;

// ws layout (floats): qhw [16384][64] (4MB) | khw [16][64][1024] (4MB)
//                     | tbl bf16 [2][64][256] pre-swizzled (64KB) | G f32 [64][64]

__device__ __forceinline__ bf16x8 cvt8(const float4& a, const float4& b) {
    bf16x8 r;
    r[0]=(__bf16)a.x; r[1]=(__bf16)a.y; r[2]=(__bf16)a.z; r[3]=(__bf16)a.w;
    r[4]=(__bf16)b.x; r[5]=(__bf16)b.y; r[6]=(__bf16)b.z; r[7]=(__bf16)b.w;
    return r;
}

__device__ __forceinline__ void gload_lds16(const void* g, void* l) {
    __builtin_amdgcn_global_load_lds(
        (const __attribute__((address_space(1))) unsigned int*)g,
        (__attribute__((address_space(3))) unsigned int*)l,
        16, 0, 0);
}

// EHW row r: r<32 -> embed[r*32][col..]; r>=32 -> embed[r-32][col..] - embed[0][col..]
__device__ __forceinline__ bf16x8 ehw_row(const float* __restrict__ embed, int r,
                                          int col, const float4& z0, const float4& z1) {
    int srcrow = (r < 32) ? (r << 5) : (r - 32);
    const float* sp = embed + (size_t)srcrow * DD + col;
    float4 a = *(const float4*)sp;
    float4 b = *(const float4*)(sp + 4);
    if (r >= 32) {
        a.x -= z0.x; a.y -= z0.y; a.z -= z0.z; a.w -= z0.w;
        b.x -= z1.x; b.y -= z1.y; b.z -= z1.z; b.w -= z1.w;
    }
    return cvt8(a, b);
}

// ---------- prep: blocks 0..15 build pre-swizzled bf16 table; block 16 builds G ----
__global__ __launch_bounds__(256) void prep(
    const float* __restrict__ embed, unsigned short* __restrict__ tbl,
    float* __restrict__ G)
{
    const int tid = threadIdx.x;
    if (blockIdx.x < 16) {
        int g = blockIdx.x * 256 + tid;        // 0..4095
        int row = g >> 6;                      // 0..63
        int c8  = (g & 63) * 8;                // 0..504
        float4 z0 = *(const float4*)(embed + c8);
        float4 z1 = *(const float4*)(embed + c8 + 4);
        bf16x8 r = ehw_row(embed, row, c8, z0, z1);
        int h  = c8 >> 8;
        int cl = c8 & 255;
        int byte = (cl * 2) ^ ((row & 7) << 4);          // bake LDS swizzle
        *(bf16x8*)((char*)tbl + h * 32768 + row * 512 + byte) = r;
    } else {
        // G = EHW . EHW^T (64x64)
        const int lane = tid & 63, wid = tid >> 6;
        const int lr = lane & 15, kq = (lane >> 4) * 8;
        f32x4 acc[4];
        #pragma unroll
        for (int n = 0; n < 4; ++n) acc[n] = (f32x4)0.0f;
        for (int ks = 0; ks < 16; ++ks) {
            int col = ks * 32 + kq;
            float4 z0 = *(const float4*)(embed + col);
            float4 z1 = *(const float4*)(embed + col + 4);
            bf16x8 af = ehw_row(embed, wid * 16 + lr, col, z0, z1);
            #pragma unroll
            for (int n = 0; n < 4; ++n) {
                bf16x8 bf = ehw_row(embed, n * 16 + lr, col, z0, z1);
                acc[n] = __builtin_amdgcn_mfma_f32_16x16x32_bf16(af, bf, acc[n], 0, 0, 0);
            }
        }
        int row0 = wid * 16 + (lane >> 4) * 4;
        #pragma unroll
        for (int n = 0; n < 4; ++n)
            #pragma unroll
            for (int i = 0; i < 4; ++i)
                G[(size_t)(row0 + i) * 64 + n * 16 + lr] = acc[n][i];
    }
}

// ---------- rank_gemm: software-pipelined stream, full 64KB table, 1 barrier ----
// blocks 0..255:  qhw[P][m]    = q[P,:]·EHW[m,:]       (64 P-rows per block)
// blocks 256..511: khw[b][m][Q] = EHW[m,:]·k[b,Q,:]    (64 Q-rows per block)
template<int GSEL>
__device__ __forceinline__ void gemm_loop(
    const float* __restrict__ srcA, const unsigned short* T,
    int lr, int kq, float4 pa[PF], float4 pb[PF], f32x4 acc[4])
{
    #pragma unroll
    for (int ks = 0; ks < 16; ++ks) {
        const int slot = ks % PF;
        bf16x8 sf = cvt8(pa[slot], pb[slot]);
        if (ks + PF < 16) {
            pa[slot] = *(const float4*)(srcA + (ks + PF) * 32);
            pb[slot] = *(const float4*)(srcA + (ks + PF) * 32 + 4);
        }
        const char* Th = (const char*)T + (ks >> 3) * 32768;
        const int kb = ((ks & 7) * 32 + kq) * 2;
        bf16x8 ef[4];
        #pragma unroll
        for (int n = 0; n < 4; ++n) {
            int row = n * 16 + lr;
            ef[n] = *(const bf16x8*)(Th + row * 512 + (kb ^ ((row & 7) << 4)));
        }
        #pragma unroll
        for (int n = 0; n < 4; ++n)
            acc[n] = GSEL
                ? __builtin_amdgcn_mfma_f32_16x16x32_bf16(ef[n], sf, acc[n], 0, 0, 0)
                : __builtin_amdgcn_mfma_f32_16x16x32_bf16(sf, ef[n], acc[n], 0, 0, 0);
    }
}

__global__ __launch_bounds__(256) void rank_gemm(
    const float* __restrict__ q, const float* __restrict__ kin,
    const unsigned short* __restrict__ tbl,
    float* __restrict__ qhw, float* __restrict__ khw)
{
    __shared__ __align__(16) unsigned short T[64 * 512];   // 64 KB full table

    const int tid = threadIdx.x, lane = tid & 63, wid = tid >> 6;
    const int lr = lane & 15, kq = (lane >> 4) * 8;
    const int gsel = blockIdx.x >> 8;
    const int tile = blockIdx.x & 255;

    // stage full table via DMA (16 x 16B per thread)
    #pragma unroll
    for (int c = 0; c < 16; ++c) {
        int off = c * 4096 + tid * 16;
        gload_lds16((const char*)tbl + off, (char*)T + off);
    }

    const int grow = tile * 64 + wid * 16 + lr;
    const float* srcA = (gsel ? kin : q) + (size_t)grow * DD + kq;

    // stream prologue: issue PF steps of loads; they overlap the table DMA
    float4 pa[PF], pb[PF];
    #pragma unroll
    for (int d = 0; d < PF; ++d) {
        pa[d] = *(const float4*)(srcA + d * 32);
        pb[d] = *(const float4*)(srcA + d * 32 + 4);
    }

    f32x4 acc[4];
    #pragma unroll
    for (int n = 0; n < 4; ++n) acc[n] = (f32x4)0.0f;

    __syncthreads();   // table resident (drains DMA; prologue loads also done)

    if (!gsel) gemm_loop<0>(srcA, T, lr, kq, pa, pb, acc);
    else       gemm_loop<1>(srcA, T, lr, kq, pa, pb, acc);

    if (!gsel) {
        // C row -> streamed P, C col -> table m
        float* o = qhw + (size_t)(tile * 64 + wid * 16 + (lane >> 4) * 4) * 64 + lr;
        #pragma unroll
        for (int n = 0; n < 4; ++n)
            #pragma unroll
            for (int i = 0; i < 4; ++i)
                o[(size_t)i * 64 + n * 16] = acc[n][i];
    } else {
        // C row -> table m, C col -> streamed Q
        int b = grow >> 10, Q = grow & 1023;
        float* o = khw + (size_t)b * 65536 + Q;
        int m0 = (lane >> 4) * 4;
        #pragma unroll
        for (int n = 0; n < 4; ++n)
            #pragma unroll
            for (int i = 0; i < 4; ++i)
                o[(size_t)(n * 16 + m0 + i) * 1024] = acc[n][i];
    }
}

// ---------- assemble: minimal writer ----------
// out[b][P=(i,j)][Q=(kq,lq)] = kh[i][Q] + kw[j][Q] + d1[jj][kq] + d2[jj][lq]
__global__ __launch_bounds__(256) void assemble(
    const float* __restrict__ qhw, const float* __restrict__ khw,
    const float* __restrict__ G, float* __restrict__ out)
{
    __shared__ __align__(16) float kh[NP];     // 4 KB
    __shared__ __align__(16) float d1[16][32];
    __shared__ __align__(16) float d2[16][32];

    const int tid = threadIdx.x, wid = tid >> 6, lane = tid & 63;
    const int b  = blockIdx.x >> 6;
    const int i  = (blockIdx.x >> 1) & 31;
    const int jh = blockIdx.x & 1;

    gload_lds16((const char*)(khw + (size_t)b * 65536 + (size_t)i * 1024)
                    + wid * 1024 + lane * 16,
                (char*)kh + wid * 1024);

    {
        int jj = tid >> 4, c = tid & 15;
        int j  = jh * 16 + jj;
        size_t Prow = (size_t)b * NP + i * 32 + j;
        const float* qA = qhw + Prow * 64;
        const float* Gi = G + (size_t)i * 64;
        const float* Gj = G + (size_t)(32 + j) * 64;
        d1[jj][c]      = qA[c]      + Gi[c]      + Gj[c];
        d1[jj][c + 16] = qA[c + 16] + Gi[c + 16] + Gj[c + 16];
        d2[jj][c]      = qA[32 + c] + Gi[32 + c] + Gj[32 + c];
        d2[jj][c + 16] = qA[48 + c] + Gi[48 + c] + Gj[48 + c];
    }
    __syncthreads();

    const int Q0 = tid * 4;
    const int kidx = Q0 >> 5;
    const int lidx = Q0 & 31;
    const float4 khv = *(const float4*)&kh[Q0];

    float* orow = out + ((size_t)b * NP + i * 32 + jh * 16) * NP + Q0;
    const float* kwb = khw + (size_t)b * 65536 + (size_t)(32 + jh * 16) * 1024 + Q0;

    #pragma unroll 4
    for (int jj = 0; jj < 16; ++jj) {
        float4 kw = *(const float4*)(kwb + (size_t)jj * 1024);
        float  s1 = d1[jj][kidx];
        float4 s2 = *(const float4*)&d2[jj][lidx];
        f32x4 v;
        v.x = khv.x + kw.x + s1 + s2.x;
        v.y = khv.y + kw.y + s1 + s2.y;
        v.z = khv.z + kw.z + s1 + s2.z;
        v.w = khv.w + kw.w + s1 + s2.w;
        __builtin_nontemporal_store(v, (f32x4*)(orow + (size_t)jj * NP));
    }
}

extern "C" void kernel_launch(void* const* d_in, const int* in_sizes, int n_in,
                              void* d_out, int out_size, void* d_ws, size_t ws_size,
                              hipStream_t stream) {
    const float* q = (const float*)d_in[0];
    const float* k = (const float*)d_in[1];
    const float* e = (const float*)d_in[2];
    float* out = (float*)d_out;

    float* qhw = (float*)d_ws;                                    // 4 MB
    float* khw = qhw + (size_t)NB * NP * 64;                      // 4 MB
    unsigned short* tbl = (unsigned short*)(khw + (size_t)NB * 64 * NP); // 64 KB
    float* G = (float*)((char*)tbl + 65536);                      // 16 KB

    hipLaunchKernelGGL(prep,      dim3(17),  dim3(256), 0, stream, e, tbl, G);
    hipLaunchKernelGGL(rank_gemm, dim3(512), dim3(256), 0, stream, q, k, tbl, qhw, khw);
    hipLaunchKernelGGL(assemble,  dim3(1024), dim3(256), 0, stream, qhw, khw, G, out);
}